// Round 3
// baseline (106.947 us; speedup 1.0000x reference)
//
#include <hip/hip_runtime.h>
#include <cstddef>

#define T_LEN 4096
#define BATCH 4
#define HID   1024
#define NS    16
#define ROWS  (BATCH*T_LEN)   // 16384
#define CHUNK 32
#define NCH   (T_LEN/CHUNK)   // 128

// workspace float offsets
#define OFF_AD   0        // A_d               [16][16]
#define OFF_X    512      // dt*phi1(A dt)     [16][16]
#define OFF_P    1024     // P_k = A_d^k, k=1..32  [32][16][16]
#define OFF_BD   16384    // B_d               [16][1024]
#define OFF_U    65536    // local/global states [16384][16]
#define OFF_LEND 327680   // chunk-end local states [4][128][16]
#define OFF_CIN  335872   // carry-in per chunk     [4][128][16]

// ---------- setup: dt, A_d = expm(A dt), dt*phi1, powers P_1..P_32 ----------
__global__ __launch_bounds__(256) void setup_kernel(const float* __restrict__ A,
                                                    const float* __restrict__ log_dt,
                                                    float* __restrict__ ws) {
    __shared__ float red[256];
    __shared__ float Ms[256], term[256], E[256], G[256];
    __shared__ float Pl[32*256];   // 32 KB: Pl[k] = A_d^{k+1}
    const int tid = threadIdx.x;

    // dt = mean(exp(log_dt))
    float s = 0.f;
    for (int i = tid; i < HID; i += 256) s += expf(log_dt[i]);
    red[tid] = s;
    __syncthreads();
    for (int w = 128; w > 0; w >>= 1) {
        if (tid < w) red[tid] += red[tid + w];
        __syncthreads();
    }
    const float dt = red[0] * (1.f/1024.f);

    const int r = tid >> 4, c = tid & 15;
    const float ident = (r == c) ? 1.f : 0.f;
    Ms[tid]   = A[tid] * (dt * (1.f/64.f));
    term[tid] = ident;
    E[tid]    = ident;   // expm accumulator
    G[tid]    = ident;   // phi1 accumulator
    __syncthreads();

    for (int i = 1; i <= 12; ++i) {
        float v = 0.f;
        #pragma unroll
        for (int m = 0; m < NS; ++m) v += term[r*16+m] * Ms[m*16+c];
        v /= (float)i;
        __syncthreads();
        term[tid] = v;
        E[tid] += v;
        G[tid] += v * (1.f/(float)(i+1));
        __syncthreads();
    }
    // 6 doublings: G <- 0.5*G*(E+I); E <- E*E
    for (int d = 0; d < 6; ++d) {
        float ge = 0.f, ee = 0.f;
        #pragma unroll
        for (int m = 0; m < NS; ++m) {
            ge += G[r*16+m] * (E[m*16+c] + ((m==c)?1.f:0.f));
            ee += E[r*16+m] * E[m*16+c];
        }
        __syncthreads();
        G[tid] = 0.5f * ge;
        E[tid] = ee;
        __syncthreads();
    }
    ws[OFF_AD + tid] = E[tid];
    ws[OFF_X  + tid] = dt * G[tid];
    Pl[tid] = E[tid];                 // P_1
    __syncthreads();
    // powers by doubling up to P_32
    for (int pm = 1; pm < 32; pm <<= 1) {
        for (int idx = tid; idx < pm*256; idx += 256) {
            const int j = idx >> 8, e = idx & 255, rr = e >> 4, cc = e & 15;
            float v = 0.f;
            #pragma unroll
            for (int m = 0; m < NS; ++m)
                v += Pl[j*256 + rr*16 + m] * Pl[(pm-1)*256 + m*16 + cc];
            Pl[(pm + j)*256 + e] = v;
        }
        __syncthreads();
    }
    for (int i = tid*4; i < 32*256; i += 1024)
        *(float4*)(ws + OFF_P + i) = *(const float4*)(&Pl[i]);
}

// ---------- B_d = (dt*phi1) @ B   [16][1024] ----------
__global__ __launch_bounds__(256) void bd_kernel(const float* __restrict__ B,
                                                 float* __restrict__ ws) {
    __shared__ float Xs[256];
    const int tid = threadIdx.x;
    Xs[tid] = ws[OFF_X + tid];
    __syncthreads();
    const int idx = blockIdx.x * 256 + tid;
    const int n = idx >> 10, h = idx & 1023;
    float a = 0.f;
    #pragma unroll
    for (int m = 0; m < NS; ++m) a += Xs[n*16+m] * B[m*HID + h];
    ws[OFF_BD + n*HID + h] = a;
}

// ---------- K1: u = x @ B_d^T + local chunk scan (32 rows/block) ----------
// 256 thr: position (rg 0..7, ng 0..3) x h-split hq = tid>>5 (0..7)
// thread computes rows {rg+8i, i=0..3} x n {4ng..4ng+3} over its 4-h slice
__global__ __launch_bounds__(256, 2) void k1_kernel(const float* __restrict__ x,
                                                    float* __restrict__ ws) {
    __shared__ __align__(16) float4 xs4[32*8];      // swizzled x tile, 4 KB
    __shared__ __align__(16) float red[4*32*16];    // cross-wave reduce, 8 KB
    __shared__ __align__(16) float us[32*16];       // u -> local states, 2 KB
    const int tid = threadIdx.x;
    const int row0 = blockIdx.x * 32;
    const int hq = tid >> 5;            // 0..7
    const int rg = (tid >> 2) & 7;      // rowgroup
    const int ng = tid & 3;             // n-quad
    const int srow = tid >> 3;          // staging row 0..31
    const int shq  = tid & 7;           // staging h-quad 0..7

    const float* xp = x + (size_t)(row0 + srow)*HID + shq*4;
    const float* bbase = ws + OFF_BD + (size_t)(4*ng)*HID + hq*4;

    float4 xa = *(const float4*)xp;
    float4 xb = *(const float4*)(xp + 32);
    float acc[4][4];
    #pragma unroll
    for (int i = 0; i < 4; ++i)
        #pragma unroll
        for (int j = 0; j < 4; ++j) acc[i][j] = 0.f;

    for (int kc = 0; kc < 32; ++kc) {
        xs4[srow*8 + (shq ^ (srow & 7))] = xa;
        __syncthreads();
        xa = xb;
        if (kc + 2 < 32) xb = *(const float4*)(xp + (kc + 2)*32);
        // Bd direct from global (L1/L2-hot, broadcast across rg lanes)
        float4 bv0 = *(const float4*)(bbase + 0*HID + kc*32);
        float4 bv1 = *(const float4*)(bbase + 1*HID + kc*32);
        float4 bv2 = *(const float4*)(bbase + 2*HID + kc*32);
        float4 bv3 = *(const float4*)(bbase + 3*HID + kc*32);
        #pragma unroll
        for (int i = 0; i < 4; ++i) {
            const int row = rg + 8*i;
            float4 xv = xs4[row*8 + (hq ^ rg)];
            acc[i][0] += xv.x*bv0.x + xv.y*bv0.y + xv.z*bv0.z + xv.w*bv0.w;
            acc[i][1] += xv.x*bv1.x + xv.y*bv1.y + xv.z*bv1.z + xv.w*bv1.w;
            acc[i][2] += xv.x*bv2.x + xv.y*bv2.y + xv.z*bv2.z + xv.w*bv2.w;
            acc[i][3] += xv.x*bv3.x + xv.y*bv3.y + xv.z*bv3.z + xv.w*bv3.w;
        }
        __syncthreads();
    }
    // reduce 8-way h-split: intra-wave pair (hq lsb = lane bit 5)
    #pragma unroll
    for (int i = 0; i < 4; ++i)
        #pragma unroll
        for (int j = 0; j < 4; ++j) acc[i][j] += __shfl_xor(acc[i][j], 32);
    const int w = tid >> 6;
    if ((tid & 32) == 0) {
        const int pos = tid & 31;
        #pragma unroll
        for (int i = 0; i < 4; ++i)
            *(float4*)(&red[(w*32 + pos)*16 + i*4]) =
                make_float4(acc[i][0], acc[i][1], acc[i][2], acc[i][3]);
    }
    __syncthreads();
    if (tid < 128) {
        const int pos = tid & 31, i = tid >> 5;
        float4 s = make_float4(0.f, 0.f, 0.f, 0.f);
        #pragma unroll
        for (int ww = 0; ww < 4; ++ww) {
            float4 p = *(const float4*)(&red[(ww*32 + pos)*16 + i*4]);
            s.x += p.x; s.y += p.y; s.z += p.z; s.w += p.w;
        }
        const int rg2 = pos >> 2, ng2 = pos & 3, row = rg2 + 8*i;
        *(float4*)(&us[row*16 + ng2*4]) = s;
    }
    __syncthreads();
    // local scan over 32 steps (wave 0, m-split 4-way)
    if (tid < 64) {
        const int n = tid & 15, mg = tid >> 4;
        const float a0 = ws[OFF_AD + (mg*4+0)*16 + n];
        const float a1 = ws[OFF_AD + (mg*4+1)*16 + n];
        const float a2 = ws[OFF_AD + (mg*4+2)*16 + n];
        const float a3 = ws[OFF_AD + (mg*4+3)*16 + n];
        float v = 0.f;
        for (int t = 0; t < CHUNK; ++t) {
            const float u0 = us[t*16 + n];
            float q = __shfl(v, mg*4+0, 16)*a0 + __shfl(v, mg*4+1, 16)*a1
                    + __shfl(v, mg*4+2, 16)*a2 + __shfl(v, mg*4+3, 16)*a3;
            q += __shfl_xor(q, 16);
            q += __shfl_xor(q, 32);
            v = u0 + q;
            if (mg == 0) us[t*16 + n] = v;
        }
        if (mg == 0) {
            const int b = row0 >> 12, cch = (row0 >> 5) & (NCH-1);
            ws[OFF_LEND + (b*NCH + cch)*16 + n] = v;
        }
    }
    __syncthreads();
    if (tid < 128) {
        const int j = tid >> 2, nq = (tid & 3)*4;
        *(float4*)(ws + OFF_U + (size_t)(row0 + j)*16 + nq) = *(const float4*)(&us[j*16 + nq]);
    }
}

// ---------- scan2: carry across 128 chunks ----------
__global__ __launch_bounds__(256) void scan2_kernel(const float* __restrict__ state,
                                                    float* __restrict__ ws,
                                                    float* __restrict__ out) {
    __shared__ float le[4*NCH*16];   // 32 KB
    const int tid = threadIdx.x;
    for (int i = tid*4; i < 4*NCH*16; i += 1024)
        *(float4*)(&le[i]) = *(const float4*)(ws + OFF_LEND + i);
    __syncthreads();
    const int b = tid >> 6;
    const int lane = tid & 63;
    const int n = lane & 15, mg = lane >> 4;
    const float p0 = ws[OFF_P + 31*256 + (mg*4+0)*16 + n];   // P_32
    const float p1 = ws[OFF_P + 31*256 + (mg*4+1)*16 + n];
    const float p2 = ws[OFF_P + 31*256 + (mg*4+2)*16 + n];
    const float p3 = ws[OFF_P + 31*256 + (mg*4+3)*16 + n];
    float v = state[b*16 + n];
    #pragma unroll 4
    for (int c = 0; c < NCH; ++c) {
        if (mg == 0) ws[OFF_CIN + (b*NCH + c)*16 + n] = v;
        float q = __shfl(v, mg*4+0, 16)*p0 + __shfl(v, mg*4+1, 16)*p1
                + __shfl(v, mg*4+2, 16)*p2 + __shfl(v, mg*4+3, 16)*p3;
        q += __shfl_xor(q, 16);
        q += __shfl_xor(q, 32);
        v = le[(b*NCH + c)*16 + n] + q;
    }
    if (mg == 0) out[(size_t)ROWS*HID + b*16 + n] = v;   // final_state
}

// ---------- K2: states = local + P_{j+1}*cin, out = states @ C^T ----------
__global__ __launch_bounds__(256, 2) void k2_kernel(const float* __restrict__ C,
                                                    const float* __restrict__ ws,
                                                    float* __restrict__ out) {
    __shared__ __align__(16) float st[32*16];
    __shared__ float cin_s[16];
    const int tid = threadIdx.x;
    const int row0 = blockIdx.x * 32;
    const int b = row0 >> 12, cch = (row0 >> 5) & (NCH-1);

    if (tid < 16) cin_s[tid] = ws[OFF_CIN + (b*NCH + cch)*16 + tid];

    float Creg[4][16];
    #pragma unroll
    for (int k = 0; k < 4; ++k) {
        #pragma unroll
        for (int q = 0; q < 4; ++q) {
            float4 cv = *(const float4*)(C + (size_t)(4*tid + k)*16 + 4*q);
            Creg[k][4*q+0] = cv.x; Creg[k][4*q+1] = cv.y;
            Creg[k][4*q+2] = cv.z; Creg[k][4*q+3] = cv.w;
        }
    }
    __syncthreads();
    if (tid < 128) {
        const int j = tid >> 2, n4 = (tid & 3)*4;
        float4 ls = *(const float4*)(ws + OFF_U + (size_t)(row0 + j)*16 + n4);
        const float* P = ws + OFF_P + j*256 + n4;   // P_{j+1}
        float cx=0.f, cy=0.f, cz=0.f, cw=0.f;
        #pragma unroll
        for (int m = 0; m < NS; ++m) {
            const float cm = cin_s[m];
            float4 pv = *(const float4*)(P + m*16);
            cx += cm*pv.x; cy += cm*pv.y; cz += cm*pv.z; cw += cm*pv.w;
        }
        *(float4*)(&st[j*16 + n4]) = make_float4(ls.x+cx, ls.y+cy, ls.z+cz, ls.w+cw);
    }
    __syncthreads();
    for (int rr = 0; rr < 32; ++rr) {
        float sv[16];
        #pragma unroll
        for (int q = 0; q < 4; ++q) {
            float4 s4 = *(const float4*)(&st[rr*16 + 4*q]);
            sv[4*q+0]=s4.x; sv[4*q+1]=s4.y; sv[4*q+2]=s4.z; sv[4*q+3]=s4.w;
        }
        float ov[4];
        #pragma unroll
        for (int k = 0; k < 4; ++k) {
            float a = 0.f;
            #pragma unroll
            for (int nn = 0; nn < NS; ++nn) a += sv[nn] * Creg[k][nn];
            ov[k] = a;
        }
        *(float4*)(out + (size_t)(row0+rr)*HID + 4*tid) = make_float4(ov[0],ov[1],ov[2],ov[3]);
    }
}

extern "C" void kernel_launch(void* const* d_in, const int* in_sizes, int n_in,
                              void* d_out, int out_size, void* d_ws, size_t ws_size,
                              hipStream_t stream) {
    const float* x      = (const float*)d_in[0];
    const float* state  = (const float*)d_in[1];
    const float* A      = (const float*)d_in[2];
    const float* B      = (const float*)d_in[3];
    const float* C      = (const float*)d_in[4];
    const float* log_dt = (const float*)d_in[5];
    float* out = (float*)d_out;
    float* ws  = (float*)d_ws;

    setup_kernel<<<1, 256, 0, stream>>>(A, log_dt, ws);
    bd_kernel   <<<64, 256, 0, stream>>>(B, ws);
    k1_kernel   <<<ROWS/32, 256, 0, stream>>>(x, ws);
    scan2_kernel<<<1, 256, 0, stream>>>(state, ws, out);
    k2_kernel   <<<ROWS/32, 256, 0, stream>>>(C, ws, out);
}

// Round 4
// 87.663 us; speedup vs baseline: 1.2200x; 1.2200x over previous
//
#include <hip/hip_runtime.h>
#include <cstddef>

#define T_LEN 4096
#define BATCH 4
#define HID   1024
#define NS    16
#define ROWS  (BATCH*T_LEN)   // 16384
#define CHUNK 32
#define NCH   (T_LEN/CHUNK)   // 128

// workspace float offsets
#define OFF_AD   0        // A_d               [16][16]
#define OFF_X    512      // dt*phi1(A dt)     [16][16]
#define OFF_P    1024     // P_k = A_d^k, k=1..32  [32][16][16]
#define OFF_BD   16384    // B_d f32           [16][1024]
#define OFF_BDH  32768    // B_d bf16          [16][1024] (2B elems)
#define OFF_U    65536    // local/global states [16384][16]
#define OFF_LEND 327680   // chunk-end local states [4][128][16]
#define OFF_CIN  335872   // carry-in per chunk     [4][128][16]

typedef __bf16 v8bf  __attribute__((ext_vector_type(8)));
typedef float  f32x4 __attribute__((ext_vector_type(4)));

// ---------- setup: dt, A_d = expm(A dt), dt*phi1, powers P_1..P_32 ----------
__global__ __launch_bounds__(256) void setup_kernel(const float* __restrict__ A,
                                                    const float* __restrict__ log_dt,
                                                    float* __restrict__ ws) {
    __shared__ float red[256];
    __shared__ float Ms[256], term[256], E[256], G[256];
    __shared__ float Pl[32*256];   // 32 KB: Pl[k] = A_d^{k+1}
    const int tid = threadIdx.x;

    // dt = mean(exp(log_dt))
    float s = 0.f;
    for (int i = tid; i < HID; i += 256) s += expf(log_dt[i]);
    red[tid] = s;
    __syncthreads();
    for (int w = 128; w > 0; w >>= 1) {
        if (tid < w) red[tid] += red[tid + w];
        __syncthreads();
    }
    const float dt = red[0] * (1.f/1024.f);

    const int r = tid >> 4, c = tid & 15;
    const float ident = (r == c) ? 1.f : 0.f;
    Ms[tid]   = A[tid] * (dt * (1.f/64.f));
    term[tid] = ident;
    E[tid]    = ident;   // expm accumulator
    G[tid]    = ident;   // phi1 accumulator
    __syncthreads();

    for (int i = 1; i <= 12; ++i) {
        float v = 0.f;
        #pragma unroll
        for (int m = 0; m < NS; ++m) v += term[r*16+m] * Ms[m*16+c];
        v /= (float)i;
        __syncthreads();
        term[tid] = v;
        E[tid] += v;
        G[tid] += v * (1.f/(float)(i+1));
        __syncthreads();
    }
    // 6 doublings: G <- 0.5*G*(E+I); E <- E*E
    for (int d = 0; d < 6; ++d) {
        float ge = 0.f, ee = 0.f;
        #pragma unroll
        for (int m = 0; m < NS; ++m) {
            ge += G[r*16+m] * (E[m*16+c] + ((m==c)?1.f:0.f));
            ee += E[r*16+m] * E[m*16+c];
        }
        __syncthreads();
        G[tid] = 0.5f * ge;
        E[tid] = ee;
        __syncthreads();
    }
    ws[OFF_AD + tid] = E[tid];
    ws[OFF_X  + tid] = dt * G[tid];
    Pl[tid] = E[tid];                 // P_1
    __syncthreads();
    // powers by doubling up to P_32
    for (int pm = 1; pm < 32; pm <<= 1) {
        for (int idx = tid; idx < pm*256; idx += 256) {
            const int j = idx >> 8, e = idx & 255, rr = e >> 4, cc = e & 15;
            float v = 0.f;
            #pragma unroll
            for (int m = 0; m < NS; ++m)
                v += Pl[j*256 + rr*16 + m] * Pl[(pm-1)*256 + m*16 + cc];
            Pl[(pm + j)*256 + e] = v;
        }
        __syncthreads();
    }
    for (int i = tid*4; i < 32*256; i += 1024)
        *(float4*)(ws + OFF_P + i) = *(const float4*)(&Pl[i]);
}

// ---------- B_d = (dt*phi1) @ B   [16][1024], f32 + bf16 copies ----------
__global__ __launch_bounds__(256) void bd_kernel(const float* __restrict__ B,
                                                 float* __restrict__ ws) {
    __shared__ float Xs[256];
    const int tid = threadIdx.x;
    Xs[tid] = ws[OFF_X + tid];
    __syncthreads();
    const int idx = blockIdx.x * 256 + tid;
    const int n = idx >> 10, h = idx & 1023;
    float a = 0.f;
    #pragma unroll
    for (int m = 0; m < NS; ++m) a += Xs[n*16+m] * B[m*HID + h];
    ws[OFF_BD + n*HID + h] = a;
    __bf16* bdh = (__bf16*)(ws + OFF_BDH);
    bdh[n*HID + h] = (__bf16)a;
}

// ---------- K1: u = x @ B_d^T via MFMA (bf16) + local chunk scan ----------
// block = 32 rows, 256 thr = 4 waves. wave w: rows 16*(w&1).., k-half (w>>1).
// No LDS/barriers in the K loop.
__global__ __launch_bounds__(256, 2) void k1_kernel(const float* __restrict__ x,
                                                    float* __restrict__ ws) {
    __shared__ __align__(16) float red[4*16*16];   // per-wave partial tiles, 4 KB
    __shared__ __align__(16) float us[32*16];      // u -> local states, 2 KB
    const int tid  = threadIdx.x;
    const int w    = tid >> 6;
    const int lane = tid & 63;
    const int row0 = blockIdx.x * 32;
    const int rhalf = w & 1;            // row half: rows 16*rhalf..
    const int khalf = w >> 1;           // k half: 512*khalf..
    const int lr = lane & 15;           // fragment row / col index
    const int lk = (lane >> 4) * 8;     // fragment k offset (contiguous 8)

    const float*  xp  = x + (size_t)(row0 + rhalf*16 + lr)*HID + khalf*512 + lk;
    const __bf16* bp  = (const __bf16*)(ws + OFF_BDH) + (size_t)lr*HID + khalf*512 + lk;

    f32x4 acc = {0.f, 0.f, 0.f, 0.f};
    #pragma unroll 4
    for (int kk = 0; kk < 16; ++kk) {
        float4 xa = *(const float4*)(xp + kk*32);
        float4 xb = *(const float4*)(xp + kk*32 + 4);
        v8bf a;
        a[0] = (__bf16)xa.x; a[1] = (__bf16)xa.y; a[2] = (__bf16)xa.z; a[3] = (__bf16)xa.w;
        a[4] = (__bf16)xb.x; a[5] = (__bf16)xb.y; a[6] = (__bf16)xb.z; a[7] = (__bf16)xb.w;
        v8bf b = *(const v8bf*)(bp + kk*32);
        acc = __builtin_amdgcn_mfma_f32_16x16x32_bf16(a, b, acc, 0, 0, 0);
    }
    // stash per-wave 16x16 tile: D row=(lane>>4)*4+reg, col=lane&15
    #pragma unroll
    for (int rreg = 0; rreg < 4; ++rreg)
        red[w*256 + ((lane>>4)*4 + rreg)*16 + lr] = acc[rreg];
    __syncthreads();
    // combine k-halves: us[row][n] = red[rhalf][.] + red[rhalf+2][.]
    #pragma unroll
    for (int e = tid; e < 512; e += 256) {
        const int rowl = e >> 4, n = e & 15;
        const int rh = rowl >> 4, rl = rowl & 15;
        us[e] = red[rh*256 + rl*16 + n] + red[(rh+2)*256 + rl*16 + n];
    }
    __syncthreads();
    // local scan over 32 steps (wave 0, m-split 4-way)
    if (tid < 64) {
        const int n = tid & 15, mg = tid >> 4;
        const float a0 = ws[OFF_AD + (mg*4+0)*16 + n];
        const float a1 = ws[OFF_AD + (mg*4+1)*16 + n];
        const float a2 = ws[OFF_AD + (mg*4+2)*16 + n];
        const float a3 = ws[OFF_AD + (mg*4+3)*16 + n];
        float v = 0.f;
        for (int t = 0; t < CHUNK; ++t) {
            const float u0 = us[t*16 + n];
            float q = __shfl(v, mg*4+0, 16)*a0 + __shfl(v, mg*4+1, 16)*a1
                    + __shfl(v, mg*4+2, 16)*a2 + __shfl(v, mg*4+3, 16)*a3;
            q += __shfl_xor(q, 16);
            q += __shfl_xor(q, 32);
            v = u0 + q;
            if (mg == 0) us[t*16 + n] = v;
        }
        if (mg == 0) {
            const int b = row0 >> 12, cch = (row0 >> 5) & (NCH-1);
            ws[OFF_LEND + (b*NCH + cch)*16 + n] = v;
        }
    }
    __syncthreads();
    if (tid < 128) {
        const int j = tid >> 2, nq = (tid & 3)*4;
        *(float4*)(ws + OFF_U + (size_t)(row0 + j)*16 + nq) = *(const float4*)(&us[j*16 + nq]);
    }
}

// ---------- scan2: carry across 128 chunks ----------
__global__ __launch_bounds__(256) void scan2_kernel(const float* __restrict__ state,
                                                    float* __restrict__ ws,
                                                    float* __restrict__ out) {
    __shared__ float le[4*NCH*16];   // 32 KB
    const int tid = threadIdx.x;
    for (int i = tid*4; i < 4*NCH*16; i += 1024)
        *(float4*)(&le[i]) = *(const float4*)(ws + OFF_LEND + i);
    __syncthreads();
    const int b = tid >> 6;
    const int lane = tid & 63;
    const int n = lane & 15, mg = lane >> 4;
    const float p0 = ws[OFF_P + 31*256 + (mg*4+0)*16 + n];   // P_32
    const float p1 = ws[OFF_P + 31*256 + (mg*4+1)*16 + n];
    const float p2 = ws[OFF_P + 31*256 + (mg*4+2)*16 + n];
    const float p3 = ws[OFF_P + 31*256 + (mg*4+3)*16 + n];
    float v = state[b*16 + n];
    #pragma unroll 4
    for (int c = 0; c < NCH; ++c) {
        if (mg == 0) ws[OFF_CIN + (b*NCH + c)*16 + n] = v;
        float q = __shfl(v, mg*4+0, 16)*p0 + __shfl(v, mg*4+1, 16)*p1
                + __shfl(v, mg*4+2, 16)*p2 + __shfl(v, mg*4+3, 16)*p3;
        q += __shfl_xor(q, 16);
        q += __shfl_xor(q, 32);
        v = le[(b*NCH + c)*16 + n] + q;
    }
    if (mg == 0) out[(size_t)ROWS*HID + b*16 + n] = v;   // final_state
}

// ---------- K2: states = local + P_{j+1}*cin, out = states @ C^T ----------
__global__ __launch_bounds__(256, 2) void k2_kernel(const float* __restrict__ C,
                                                    const float* __restrict__ ws,
                                                    float* __restrict__ out) {
    __shared__ __align__(16) float st[32*16];
    __shared__ float cin_s[16];
    const int tid = threadIdx.x;
    const int row0 = blockIdx.x * 32;
    const int b = row0 >> 12, cch = (row0 >> 5) & (NCH-1);

    if (tid < 16) cin_s[tid] = ws[OFF_CIN + (b*NCH + cch)*16 + tid];

    float Creg[4][16];
    #pragma unroll
    for (int k = 0; k < 4; ++k) {
        #pragma unroll
        for (int q = 0; q < 4; ++q) {
            float4 cv = *(const float4*)(C + (size_t)(4*tid + k)*16 + 4*q);
            Creg[k][4*q+0] = cv.x; Creg[k][4*q+1] = cv.y;
            Creg[k][4*q+2] = cv.z; Creg[k][4*q+3] = cv.w;
        }
    }
    __syncthreads();
    if (tid < 128) {
        const int j = tid >> 2, n4 = (tid & 3)*4;
        float4 ls = *(const float4*)(ws + OFF_U + (size_t)(row0 + j)*16 + n4);
        const float* P = ws + OFF_P + j*256 + n4;   // P_{j+1}
        float cx=0.f, cy=0.f, cz=0.f, cw=0.f;
        #pragma unroll
        for (int m = 0; m < NS; ++m) {
            const float cm = cin_s[m];
            float4 pv = *(const float4*)(P + m*16);
            cx += cm*pv.x; cy += cm*pv.y; cz += cm*pv.z; cw += cm*pv.w;
        }
        *(float4*)(&st[j*16 + n4]) = make_float4(ls.x+cx, ls.y+cy, ls.z+cz, ls.w+cw);
    }
    __syncthreads();
    for (int rr = 0; rr < 32; ++rr) {
        float sv[16];
        #pragma unroll
        for (int q = 0; q < 4; ++q) {
            float4 s4 = *(const float4*)(&st[rr*16 + 4*q]);
            sv[4*q+0]=s4.x; sv[4*q+1]=s4.y; sv[4*q+2]=s4.z; sv[4*q+3]=s4.w;
        }
        float ov[4];
        #pragma unroll
        for (int k = 0; k < 4; ++k) {
            float a = 0.f;
            #pragma unroll
            for (int nn = 0; nn < NS; ++nn) a += sv[nn] * Creg[k][nn];
            ov[k] = a;
        }
        *(float4*)(out + (size_t)(row0+rr)*HID + 4*tid) = make_float4(ov[0],ov[1],ov[2],ov[3]);
    }
}

extern "C" void kernel_launch(void* const* d_in, const int* in_sizes, int n_in,
                              void* d_out, int out_size, void* d_ws, size_t ws_size,
                              hipStream_t stream) {
    const float* x      = (const float*)d_in[0];
    const float* state  = (const float*)d_in[1];
    const float* A      = (const float*)d_in[2];
    const float* B      = (const float*)d_in[3];
    const float* C      = (const float*)d_in[4];
    const float* log_dt = (const float*)d_in[5];
    float* out = (float*)d_out;
    float* ws  = (float*)d_ws;

    setup_kernel<<<1, 256, 0, stream>>>(A, log_dt, ws);
    bd_kernel   <<<64, 256, 0, stream>>>(B, ws);
    k1_kernel   <<<ROWS/32, 256, 0, stream>>>(x, ws);
    scan2_kernel<<<1, 256, 0, stream>>>(state, ws, out);
    k2_kernel   <<<ROWS/32, 256, 0, stream>>>(C, ws, out);
}

// Round 5
// 76.499 us; speedup vs baseline: 1.3980x; 1.1459x over previous
//
#include <hip/hip_runtime.h>
#include <cstddef>

#define T_LEN 4096
#define BATCH 4
#define HID   1024
#define NS    16
#define ROWS  (BATCH*T_LEN)   // 16384
#define CHUNK 32
#define NCH   (T_LEN/CHUNK)   // 128

// workspace float offsets
#define OFF_AD   0        // A_d               [16][16]
#define OFF_X    512      // dt*phi1(A dt)     [16][16]
#define OFF_P    1024     // P_k = A_d^k, k=1..32  [32][16][16]
#define OFF_BDH  32768    // B_d bf16          [16][1024] (2B elems)
#define OFF_U    65536    // local/global states [16384][16]
#define OFF_LEND 327680   // chunk-end local states [4][128][16]
#define OFF_CIN  335872   // carry-in per chunk     [4][128][16]

typedef __bf16 v8bf  __attribute__((ext_vector_type(8)));
typedef float  f32x4 __attribute__((ext_vector_type(4)));

// ---------- setup: dt, A_d = expm(A dt), dt*phi1, powers P_1..P_32 ----------
__global__ __launch_bounds__(256) void setup_kernel(const float* __restrict__ A,
                                                    const float* __restrict__ log_dt,
                                                    float* __restrict__ ws) {
    __shared__ float red[256];
    __shared__ float Ms[256], term[256], E[256], G[256];
    __shared__ float Pl[32*256];   // 32 KB: Pl[k] = A_d^{k+1}
    const int tid = threadIdx.x;

    // dt = mean(exp(log_dt))
    float s = 0.f;
    for (int i = tid; i < HID; i += 256) s += expf(log_dt[i]);
    red[tid] = s;
    __syncthreads();
    for (int w = 128; w > 0; w >>= 1) {
        if (tid < w) red[tid] += red[tid + w];
        __syncthreads();
    }
    const float dt = red[0] * (1.f/1024.f);

    const int r = tid >> 4, c = tid & 15;
    const float ident = (r == c) ? 1.f : 0.f;
    Ms[tid]   = A[tid] * (dt * (1.f/64.f));
    term[tid] = ident;
    E[tid]    = ident;   // expm accumulator
    G[tid]    = ident;   // phi1 accumulator
    __syncthreads();

    for (int i = 1; i <= 12; ++i) {
        float v = 0.f;
        #pragma unroll
        for (int m = 0; m < NS; ++m) v += term[r*16+m] * Ms[m*16+c];
        v /= (float)i;
        __syncthreads();
        term[tid] = v;
        E[tid] += v;
        G[tid] += v * (1.f/(float)(i+1));
        __syncthreads();
    }
    // 6 doublings: G <- 0.5*G*(E+I); E <- E*E
    for (int d = 0; d < 6; ++d) {
        float ge = 0.f, ee = 0.f;
        #pragma unroll
        for (int m = 0; m < NS; ++m) {
            ge += G[r*16+m] * (E[m*16+c] + ((m==c)?1.f:0.f));
            ee += E[r*16+m] * E[m*16+c];
        }
        __syncthreads();
        G[tid] = 0.5f * ge;
        E[tid] = ee;
        __syncthreads();
    }
    ws[OFF_AD + tid] = E[tid];
    ws[OFF_X  + tid] = dt * G[tid];
    Pl[tid] = E[tid];                 // P_1
    __syncthreads();
    // powers by doubling up to P_32
    for (int pm = 1; pm < 32; pm <<= 1) {
        for (int idx = tid; idx < pm*256; idx += 256) {
            const int j = idx >> 8, e = idx & 255, rr = e >> 4, cc = e & 15;
            float v = 0.f;
            #pragma unroll
            for (int m = 0; m < NS; ++m)
                v += Pl[j*256 + rr*16 + m] * Pl[(pm-1)*256 + m*16 + cc];
            Pl[(pm + j)*256 + e] = v;
        }
        __syncthreads();
    }
    for (int i = tid*4; i < 32*256; i += 1024)
        *(float4*)(ws + OFF_P + i) = *(const float4*)(&Pl[i]);
}

// ---------- B_d = (dt*phi1) @ B   [16][1024], bf16 ----------
__global__ __launch_bounds__(256) void bd_kernel(const float* __restrict__ B,
                                                 float* __restrict__ ws) {
    __shared__ float Xs[256];
    const int tid = threadIdx.x;
    Xs[tid] = ws[OFF_X + tid];
    __syncthreads();
    const int idx = blockIdx.x * 256 + tid;
    const int n = idx >> 10, h = idx & 1023;
    float a = 0.f;
    #pragma unroll
    for (int m = 0; m < NS; ++m) a += Xs[n*16+m] * B[m*HID + h];
    __bf16* bdh = (__bf16*)(ws + OFF_BDH);
    bdh[n*HID + h] = (__bf16)a;
}

// ---------- K1: u = x @ B_d^T via MFMA + local chunk scan ----------
// 512 thr = 8 waves: rhalf = w&1 (16-row half), kslice = w>>1 (K/4 = 256)
// Full-unroll K loop in two prefetch groups; no LDS/barriers in main loop.
__global__ __launch_bounds__(512, 4) void k1_kernel(const float* __restrict__ x,
                                                    float* __restrict__ ws) {
    __shared__ __align__(16) float red[8*256];     // per-wave partial tiles, 8 KB
    __shared__ __align__(16) float us[32*16];      // u -> local states, 2 KB
    const int tid  = threadIdx.x;
    const int w    = tid >> 6;
    const int lane = tid & 63;
    const int row0 = blockIdx.x * 32;
    const int rhalf = w & 1;            // row half
    const int ks    = w >> 1;           // k slice (256 wide)
    const int lr = lane & 15;
    const int lk = (lane >> 4) * 8;

    const float*  xp  = x + (size_t)(row0 + rhalf*16 + lr)*HID + ks*256 + lk;
    const __bf16* bp  = (const __bf16*)(ws + OFF_BDH) + (size_t)lr*HID + ks*256 + lk;

    // group 0 loads (4 kk-iters)
    float4 xv0[4][2]; v8bf bv0[4];
    #pragma unroll
    for (int i = 0; i < 4; ++i) {
        xv0[i][0] = *(const float4*)(xp + i*32);
        xv0[i][1] = *(const float4*)(xp + i*32 + 4);
        bv0[i]    = *(const v8bf*)(bp + i*32);
    }
    // group 1 loads
    float4 xv1[4][2]; v8bf bv1[4];
    #pragma unroll
    for (int i = 0; i < 4; ++i) {
        xv1[i][0] = *(const float4*)(xp + 128 + i*32);
        xv1[i][1] = *(const float4*)(xp + 128 + i*32 + 4);
        bv1[i]    = *(const v8bf*)(bp + 128 + i*32);
    }

    f32x4 acc = {0.f, 0.f, 0.f, 0.f};
    #pragma unroll
    for (int i = 0; i < 4; ++i) {
        v8bf a;
        a[0]=(__bf16)xv0[i][0].x; a[1]=(__bf16)xv0[i][0].y; a[2]=(__bf16)xv0[i][0].z; a[3]=(__bf16)xv0[i][0].w;
        a[4]=(__bf16)xv0[i][1].x; a[5]=(__bf16)xv0[i][1].y; a[6]=(__bf16)xv0[i][1].z; a[7]=(__bf16)xv0[i][1].w;
        acc = __builtin_amdgcn_mfma_f32_16x16x32_bf16(a, bv0[i], acc, 0, 0, 0);
    }
    #pragma unroll
    for (int i = 0; i < 4; ++i) {
        v8bf a;
        a[0]=(__bf16)xv1[i][0].x; a[1]=(__bf16)xv1[i][0].y; a[2]=(__bf16)xv1[i][0].z; a[3]=(__bf16)xv1[i][0].w;
        a[4]=(__bf16)xv1[i][1].x; a[5]=(__bf16)xv1[i][1].y; a[6]=(__bf16)xv1[i][1].z; a[7]=(__bf16)xv1[i][1].w;
        acc = __builtin_amdgcn_mfma_f32_16x16x32_bf16(a, bv1[i], acc, 0, 0, 0);
    }

    // stash per-wave 16x16 tile: D row=(lane>>4)*4+reg, col=lane&15
    #pragma unroll
    for (int rreg = 0; rreg < 4; ++rreg)
        red[w*256 + ((lane>>4)*4 + rreg)*16 + lr] = acc[rreg];
    __syncthreads();
    // combine 4 k-slices: us[row][n]
    {
        const int rowl = tid >> 4, n = tid & 15;
        const int rh = rowl >> 4, rl = rowl & 15;
        float v = 0.f;
        #pragma unroll
        for (int kk = 0; kk < 4; ++kk)
            v += red[(rh + 2*kk)*256 + rl*16 + n];
        us[tid] = v;
    }
    __syncthreads();
    // local scan over 32 steps (wave 0, m-split 4-way)
    if (tid < 64) {
        const int n = tid & 15, mg = tid >> 4;
        const float a0 = ws[OFF_AD + (mg*4+0)*16 + n];
        const float a1 = ws[OFF_AD + (mg*4+1)*16 + n];
        const float a2 = ws[OFF_AD + (mg*4+2)*16 + n];
        const float a3 = ws[OFF_AD + (mg*4+3)*16 + n];
        float v = 0.f;
        for (int t = 0; t < CHUNK; ++t) {
            const float u0 = us[t*16 + n];
            float q = __shfl(v, mg*4+0, 16)*a0 + __shfl(v, mg*4+1, 16)*a1
                    + __shfl(v, mg*4+2, 16)*a2 + __shfl(v, mg*4+3, 16)*a3;
            q += __shfl_xor(q, 16);
            q += __shfl_xor(q, 32);
            v = u0 + q;
            if (mg == 0) us[t*16 + n] = v;
        }
        if (mg == 0) {
            const int b = row0 >> 12, cch = (row0 >> 5) & (NCH-1);
            ws[OFF_LEND + (b*NCH + cch)*16 + n] = v;
        }
    }
    __syncthreads();
    if (tid < 128) {
        const int j = tid >> 2, nq = (tid & 3)*4;
        *(float4*)(ws + OFF_U + (size_t)(row0 + j)*16 + nq) = *(const float4*)(&us[j*16 + nq]);
    }
}

// ---------- scan2: carry across 128 chunks ----------
__global__ __launch_bounds__(256) void scan2_kernel(const float* __restrict__ state,
                                                    float* __restrict__ ws,
                                                    float* __restrict__ out) {
    __shared__ float le[4*NCH*16];   // 32 KB
    const int tid = threadIdx.x;
    for (int i = tid*4; i < 4*NCH*16; i += 1024)
        *(float4*)(&le[i]) = *(const float4*)(ws + OFF_LEND + i);
    __syncthreads();
    const int b = tid >> 6;
    const int lane = tid & 63;
    const int n = lane & 15, mg = lane >> 4;
    const float p0 = ws[OFF_P + 31*256 + (mg*4+0)*16 + n];   // P_32
    const float p1 = ws[OFF_P + 31*256 + (mg*4+1)*16 + n];
    const float p2 = ws[OFF_P + 31*256 + (mg*4+2)*16 + n];
    const float p3 = ws[OFF_P + 31*256 + (mg*4+3)*16 + n];
    float v = state[b*16 + n];
    #pragma unroll 4
    for (int c = 0; c < NCH; ++c) {
        if (mg == 0) ws[OFF_CIN + (b*NCH + c)*16 + n] = v;
        float q = __shfl(v, mg*4+0, 16)*p0 + __shfl(v, mg*4+1, 16)*p1
                + __shfl(v, mg*4+2, 16)*p2 + __shfl(v, mg*4+3, 16)*p3;
        q += __shfl_xor(q, 16);
        q += __shfl_xor(q, 32);
        v = le[(b*NCH + c)*16 + n] + q;
    }
    if (mg == 0) out[(size_t)ROWS*HID + b*16 + n] = v;   // final_state
}

// ---------- K2: states = local + P_{j+1}*cin, then out = states @ C^T via MFMA ----------
// block = 32 rows (one chunk), 256 thr = 4 waves: rhalf = w&1, nhalf = w>>1
__global__ __launch_bounds__(256, 2) void k2_kernel(const float* __restrict__ C,
                                                    const float* __restrict__ ws,
                                                    float* __restrict__ out) {
    __shared__ __align__(16) float st[32*20];   // padded stride 20
    __shared__ float cin_s[16];
    const int tid = threadIdx.x;
    const int row0 = blockIdx.x * 32;
    const int b = row0 >> 12, cch = (row0 >> 5) & (NCH-1);

    if (tid < 16) cin_s[tid] = ws[OFF_CIN + (b*NCH + cch)*16 + tid];
    __syncthreads();
    // phase 1: corrected states -> st (f32, padded)
    if (tid < 128) {
        const int j = tid >> 2, n4 = (tid & 3)*4;
        float4 ls = *(const float4*)(ws + OFF_U + (size_t)(row0 + j)*16 + n4);
        const float* P = ws + OFF_P + j*256 + n4;   // P_{j+1}
        float cx=0.f, cy=0.f, cz=0.f, cw=0.f;
        #pragma unroll
        for (int m = 0; m < NS; ++m) {
            const float cm = cin_s[m];
            float4 pv = *(const float4*)(P + m*16);
            cx += cm*pv.x; cy += cm*pv.y; cz += cm*pv.z; cw += cm*pv.w;
        }
        *(float4*)(&st[j*20 + n4]) = make_float4(ls.x+cx, ls.y+cy, ls.z+cz, ls.w+cw);
    }
    __syncthreads();
    // phase 2: MFMA  out[row][h] = sum_k states[row][k] * C[h][k]
    const int w = tid >> 6, lane = tid & 63;
    const int rhalf = w & 1, nh = w >> 1;
    const int lr = lane & 15;
    const int lk = (lane >> 4) * 8;   // 0,8 real; 16,24 -> zero

    v8bf a = {};
    if (lk < 16) {
        float4 s0 = *(const float4*)(&st[(rhalf*16 + lr)*20 + lk]);
        float4 s1 = *(const float4*)(&st[(rhalf*16 + lr)*20 + lk + 4]);
        a[0]=(__bf16)s0.x; a[1]=(__bf16)s0.y; a[2]=(__bf16)s0.z; a[3]=(__bf16)s0.w;
        a[4]=(__bf16)s1.x; a[5]=(__bf16)s1.y; a[6]=(__bf16)s1.z; a[7]=(__bf16)s1.w;
    }
    const int orow = row0 + rhalf*16 + (lane>>4)*4;
    #pragma unroll 4
    for (int nt = 0; nt < 32; ++nt) {
        const int n0 = (nh*32 + nt)*16;
        v8bf bfr = {};
        if (lk < 16) {
            float4 c0 = *(const float4*)(C + (size_t)(n0 + lr)*16 + lk);
            float4 c1 = *(const float4*)(C + (size_t)(n0 + lr)*16 + lk + 4);
            bfr[0]=(__bf16)c0.x; bfr[1]=(__bf16)c0.y; bfr[2]=(__bf16)c0.z; bfr[3]=(__bf16)c0.w;
            bfr[4]=(__bf16)c1.x; bfr[5]=(__bf16)c1.y; bfr[6]=(__bf16)c1.z; bfr[7]=(__bf16)c1.w;
        }
        f32x4 acc = {0.f, 0.f, 0.f, 0.f};
        acc = __builtin_amdgcn_mfma_f32_16x16x32_bf16(a, bfr, acc, 0, 0, 0);
        #pragma unroll
        for (int rg = 0; rg < 4; ++rg)
            out[(size_t)(orow + rg)*HID + n0 + lr] = acc[rg];
    }
}

extern "C" void kernel_launch(void* const* d_in, const int* in_sizes, int n_in,
                              void* d_out, int out_size, void* d_ws, size_t ws_size,
                              hipStream_t stream) {
    const float* x      = (const float*)d_in[0];
    const float* state  = (const float*)d_in[1];
    const float* A      = (const float*)d_in[2];
    const float* B      = (const float*)d_in[3];
    const float* C      = (const float*)d_in[4];
    const float* log_dt = (const float*)d_in[5];
    float* out = (float*)d_out;
    float* ws  = (float*)d_ws;

    setup_kernel<<<1, 256, 0, stream>>>(A, log_dt, ws);
    bd_kernel   <<<64, 256, 0, stream>>>(B, ws);
    k1_kernel   <<<ROWS/32, 512, 0, stream>>>(x, ws);
    scan2_kernel<<<1, 256, 0, stream>>>(state, ws, out);
    k2_kernel   <<<ROWS/32, 256, 0, stream>>>(C, ws, out);
}